// Round 1
// baseline (1719.311 us; speedup 1.0000x reference)
//
#include <hip/hip_runtime.h>
#include <math.h>

// simple_GAT: 5-layer GAT (heads=1) + BN(eval) + mean-pool + linear.
// Structure: build CSR-by-dst once per call (histogram/scan/scatter), then per
// layer: fp32 SIMT GEMM (h@W -> xp), attention dots (xp.a_src, xp.a_dst),
// wave-per-dst-node softmax aggregation with fused bias/ReLU/BN epilogue.
// Finally segmented mean pool (batch is sorted) + 128->1 linear.

#define NN 100000
#define NE 1600000
#define DH 128
#define NL 5
#define NG 64

static constexpr int ET = NE + NN;  // edges + self loops

// ---- CSR build ------------------------------------------------------------

__global__ void k_deg(const int* __restrict__ dst, int* __restrict__ deg) {
    int i = blockIdx.x * blockDim.x + threadIdx.x;
    if (i < ET) {
        int d = (i < NE) ? dst[i] : (i - NE);
        atomicAdd(&deg[d], 1);
    }
}

__global__ __launch_bounds__(1024) void k_scan(const int* __restrict__ deg,
                                               int* __restrict__ row_ptr) {
    __shared__ int sm[1024];
    __shared__ int carry;
    int tid = threadIdx.x;
    if (tid == 0) { carry = 0; row_ptr[0] = 0; }
    __syncthreads();
    for (int base = 0; base < NN; base += 1024) {
        int i = base + tid;
        int v = (i < NN) ? deg[i] : 0;
        sm[tid] = v;
        __syncthreads();
        for (int off = 1; off < 1024; off <<= 1) {
            int t = (tid >= off) ? sm[tid - off] : 0;
            __syncthreads();
            sm[tid] += t;
            __syncthreads();
        }
        if (i < NN) row_ptr[i + 1] = sm[tid] + carry;
        __syncthreads();
        if (tid == 0) carry += sm[1023];
        __syncthreads();
    }
}

__global__ void k_scatter(const int* __restrict__ src, const int* __restrict__ dst,
                          int* __restrict__ cursor, int* __restrict__ csr_src) {
    int i = blockIdx.x * blockDim.x + threadIdx.x;
    if (i < ET) {
        int s, d;
        if (i < NE) { s = src[i]; d = dst[i]; } else { s = d = i - NE; }
        int pos = atomicAdd(&cursor[d], 1);
        csr_src[pos] = s;
    }
}

// ---- GEMM: xp = h @ W  (fp32 SIMT, BM=64, BN=128(full), BK=32) ------------

__global__ __launch_bounds__(256) void k_gemm(const float* __restrict__ A,
                                              const float* __restrict__ W,
                                              float* __restrict__ C) {
    __shared__ float hs[64][33];
    __shared__ float ws[32][128];
    int tid = threadIdx.x;
    int ty = tid >> 4, tx = tid & 15;
    int row0 = blockIdx.x * 64;
    float acc[4][8];
#pragma unroll
    for (int i = 0; i < 4; ++i)
#pragma unroll
        for (int j = 0; j < 8; ++j) acc[i][j] = 0.f;

    for (int k0 = 0; k0 < 128; k0 += 32) {
        {   // stage A tile: 64 rows x 32 k
            int r = tid >> 2;
            int cc = (tid & 3) << 3;
            int row = row0 + r;
            float4 v0 = make_float4(0.f, 0.f, 0.f, 0.f), v1 = v0;
            if (row < NN) {
                const float4* p = (const float4*)(A + (size_t)row * DH + k0 + cc);
                v0 = p[0]; v1 = p[1];
            }
            hs[r][cc + 0] = v0.x; hs[r][cc + 1] = v0.y;
            hs[r][cc + 2] = v0.z; hs[r][cc + 3] = v0.w;
            hs[r][cc + 4] = v1.x; hs[r][cc + 5] = v1.y;
            hs[r][cc + 6] = v1.z; hs[r][cc + 7] = v1.w;
        }
        {   // stage W tile: 32 k x 128 cols
            int r = tid >> 3;
            int cc = (tid & 7) << 4;
            const float4* p = (const float4*)(W + (size_t)(k0 + r) * DH + cc);
            float4* q = (float4*)&ws[r][cc];
            q[0] = p[0]; q[1] = p[1]; q[2] = p[2]; q[3] = p[3];
        }
        __syncthreads();
#pragma unroll
        for (int k = 0; k < 32; ++k) {
            float aa[4];
#pragma unroll
            for (int i = 0; i < 4; ++i) aa[i] = hs[ty * 4 + i][k];
            const float4 b0 = *(const float4*)&ws[k][tx * 8];
            const float4 b1 = *(const float4*)&ws[k][tx * 8 + 4];
            float bb[8] = {b0.x, b0.y, b0.z, b0.w, b1.x, b1.y, b1.z, b1.w};
#pragma unroll
            for (int i = 0; i < 4; ++i)
#pragma unroll
                for (int j = 0; j < 8; ++j)
                    acc[i][j] = fmaf(aa[i], bb[j], acc[i][j]);
        }
        __syncthreads();
    }
#pragma unroll
    for (int i = 0; i < 4; ++i) {
        int row = row0 + ty * 4 + i;
        if (row < NN) {
            float4 o0 = make_float4(acc[i][0], acc[i][1], acc[i][2], acc[i][3]);
            float4 o1 = make_float4(acc[i][4], acc[i][5], acc[i][6], acc[i][7]);
            float4* p = (float4*)(C + (size_t)row * DH + tx * 8);
            p[0] = o0; p[1] = o1;
        }
    }
}

// ---- attention dots: s_node = xp.a_src, d_node = xp.a_dst -----------------

__global__ __launch_bounds__(256) void k_dots(const float* __restrict__ xp,
                                              const float* __restrict__ a_s,
                                              const float* __restrict__ a_d,
                                              float* __restrict__ s_node,
                                              float* __restrict__ d_node) {
    int wid = threadIdx.x >> 6, lane = threadIdx.x & 63;
    int n = blockIdx.x * 4 + wid;
    if (n >= NN) return;
    float2 v  = ((const float2*)(xp + (size_t)n * DH))[lane];
    float2 as = ((const float2*)a_s)[lane];
    float2 ad = ((const float2*)a_d)[lane];
    float ps = v.x * as.x + v.y * as.y;
    float pd = v.x * ad.x + v.y * ad.y;
#pragma unroll
    for (int off = 32; off >= 1; off >>= 1) {
        ps += __shfl_xor(ps, off, 64);
        pd += __shfl_xor(pd, off, 64);
    }
    if (lane == 0) { s_node[n] = ps; d_node[n] = pd; }
}

// ---- aggregation: wave per dst node; fused bias/ReLU/BN -------------------

__global__ __launch_bounds__(256) void k_aggr(const float* __restrict__ xp,
                                              const float* __restrict__ s_node,
                                              const float* __restrict__ d_node,
                                              const int* __restrict__ row_ptr,
                                              const int* __restrict__ csr_src,
                                              const float* __restrict__ bias,
                                              const float* __restrict__ gamma,
                                              const float* __restrict__ beta,
                                              const float* __restrict__ mean,
                                              const float* __restrict__ var,
                                              float* __restrict__ hout) {
    int wid = threadIdx.x >> 6, lane = threadIdx.x & 63;
    int n = blockIdx.x * 4 + wid;
    if (n >= NN) return;
    int s0 = row_ptr[n], s1 = row_ptr[n + 1];
    float dn = d_node[n];
    // pass 1: segment max (lane-parallel over edges)
    float mx = -1e30f;
    for (int j = s0 + lane; j < s1; j += 64) {
        int s = csr_src[j];
        float e = s_node[s] + dn;
        e = (e >= 0.f) ? e : 0.2f * e;
        mx = fmaxf(mx, e);
    }
#pragma unroll
    for (int off = 32; off >= 1; off >>= 1)
        mx = fmaxf(mx, __shfl_xor(mx, off, 64));
    // pass 2: whole wave per edge, coalesced row gather
    float2 acc = make_float2(0.f, 0.f);
    float denom = 0.f;
    for (int j = s0; j < s1; ++j) {
        int s = csr_src[j];          // wave-uniform -> broadcast
        float e = s_node[s] + dn;
        e = (e >= 0.f) ? e : 0.2f * e;
        float w = __expf(e - mx);
        denom += w;
        float2 v = ((const float2*)(xp + (size_t)s * DH))[lane];
        acc.x += w * v.x;
        acc.y += w * v.y;
    }
    float inv = 1.f / denom;         // denom >= 1 (self-loop gives w=1 term)
    int c0 = lane * 2, c1 = c0 + 1;
    float o0 = acc.x * inv + bias[c0];
    float o1 = acc.y * inv + bias[c1];
    o0 = fmaxf(o0, 0.f);
    o1 = fmaxf(o1, 0.f);
    o0 = (o0 - mean[c0]) * (gamma[c0] * rsqrtf(var[c0] + 1e-5f)) + beta[c0];
    o1 = (o1 - mean[c1]) * (gamma[c1] * rsqrtf(var[c1] + 1e-5f)) + beta[c1];
    ((float2*)(hout + (size_t)n * DH))[lane] = make_float2(o0, o1);
}

// ---- mean pool over sorted batch + final linear ---------------------------

__global__ __launch_bounds__(128) void k_pool1(const float* __restrict__ h,
                                               const int* __restrict__ batch,
                                               float* __restrict__ sums,
                                               int* __restrict__ cnts) {
    int c = threadIdx.x;
    int n0 = blockIdx.x * 64;
    int n1 = min(NN, n0 + 64);
    if (n0 >= NN) return;
    float acc = 0.f;
    int cur = batch[n0];
    int cnt = 0;
    for (int n = n0; n < n1; ++n) {
        int g = batch[n];
        if (g != cur) {
            atomicAdd(&sums[cur * DH + c], acc);
            if (c == 0) atomicAdd(&cnts[cur], cnt);
            acc = 0.f; cnt = 0; cur = g;
        }
        acc += h[(size_t)n * DH + c];
        ++cnt;
    }
    atomicAdd(&sums[cur * DH + c], acc);
    if (c == 0) atomicAdd(&cnts[cur], cnt);
}

__global__ __launch_bounds__(128) void k_pool2(const float* __restrict__ sums,
                                               const int* __restrict__ cnts,
                                               const float* __restrict__ lin_w,
                                               const float* __restrict__ lin_b,
                                               float* __restrict__ out) {
    __shared__ float sm[128];
    int g = blockIdx.x, c = threadIdx.x;
    float cnt = fmaxf((float)cnts[g], 1.f);
    sm[c] = (sums[g * DH + c] / cnt) * lin_w[c];
    __syncthreads();
    for (int off = 64; off >= 1; off >>= 1) {
        if (c < off) sm[c] += sm[c + off];
        __syncthreads();
    }
    if (c == 0) out[g] = sm[0] + lin_b[0];
}

// ---- launch ---------------------------------------------------------------

extern "C" void kernel_launch(void* const* d_in, const int* in_sizes, int n_in,
                              void* d_out, int out_size, void* d_ws, size_t ws_size,
                              hipStream_t stream) {
    const float* x     = (const float*)d_in[0];
    const int*   ei    = (const int*)d_in[1];
    const int*   batch = (const int*)d_in[2];
    const float* W     = (const float*)d_in[3];
    const float* a_src = (const float*)d_in[4];
    const float* a_dst = (const float*)d_in[5];
    const float* b     = (const float*)d_in[6];
    const float* bn_g  = (const float*)d_in[7];
    const float* bn_b  = (const float*)d_in[8];
    const float* bn_m  = (const float*)d_in[9];
    const float* bn_v  = (const float*)d_in[10];
    const float* lin_w = (const float*)d_in[11];
    const float* lin_b = (const float*)d_in[12];
    float* out = (float*)d_out;

    const int* srcp = ei;
    const int* dstp = ei + NE;

    char* wsp = (char*)d_ws;
    size_t off = 0;
    auto alloc = [&](size_t bytes) -> void* {
        void* p = wsp + off;
        off = (off + bytes + 511) & ~((size_t)511);
        return p;
    };
    float* buf0    = (float*)alloc((size_t)NN * DH * 4);   // xp
    float* buf1    = (float*)alloc((size_t)NN * DH * 4);   // h
    float* s_node  = (float*)alloc((size_t)NN * 4);
    float* d_node  = (float*)alloc((size_t)NN * 4);
    int*   row_ptr = (int*)alloc((size_t)(NN + 1) * 4);
    int*   cursor  = (int*)alloc((size_t)NN * 4);          // also deg
    int*   csr_src = (int*)alloc((size_t)ET * 4);
    float* sums    = (float*)alloc((size_t)NG * DH * 4);
    int*   cnts    = (int*)alloc((size_t)NG * 4);

    // CSR build (reused across the 5 layers)
    hipMemsetAsync(cursor, 0, (size_t)NN * 4, stream);
    k_deg<<<(ET + 255) / 256, 256, 0, stream>>>(dstp, cursor);
    k_scan<<<1, 1024, 0, stream>>>(cursor, row_ptr);
    hipMemcpyAsync(cursor, row_ptr, (size_t)NN * 4, hipMemcpyDeviceToDevice, stream);
    k_scatter<<<(ET + 255) / 256, 256, 0, stream>>>(srcp, dstp, cursor, csr_src);

    for (int l = 0; l < NL; ++l) {
        const float* hin = (l == 0) ? x : buf1;
        k_gemm<<<(NN + 63) / 64, 256, 0, stream>>>(hin, W + (size_t)l * DH * DH, buf0);
        k_dots<<<(NN + 3) / 4, 256, 0, stream>>>(buf0, a_src + l * DH, a_dst + l * DH,
                                                 s_node, d_node);
        k_aggr<<<(NN + 3) / 4, 256, 0, stream>>>(buf0, s_node, d_node, row_ptr, csr_src,
                                                 b + l * DH, bn_g + l * DH, bn_b + l * DH,
                                                 bn_m + l * DH, bn_v + l * DH, buf1);
    }

    hipMemsetAsync(sums, 0, (size_t)NG * DH * 4, stream);
    hipMemsetAsync(cnts, 0, (size_t)NG * 4, stream);
    k_pool1<<<(NN + 63) / 64, 128, 0, stream>>>(buf1, batch, sums, cnts);
    k_pool2<<<NG, 128, 0, stream>>>(sums, cnts, lin_w, lin_b, out);
}

// Round 2
// 1428.186 us; speedup vs baseline: 1.2038x; 1.2038x over previous
//
#include <hip/hip_runtime.h>
#include <hip/hip_bf16.h>
#include <math.h>

// simple_GAT: 5-layer GAT (heads=1) + BN(eval) + mean-pool + linear.
// R2: xp stored bf16 (halves gather traffic in k_aggr), attention dots fused
// into GEMM epilogue (kills k_dots), multi-block CSR scan (kills serial scan).

#define NN 100000
#define NE 1600000
#define DH 128
#define NL 5
#define NG 64

static constexpr int ET = NE + NN;      // edges + self loops
static constexpr int NSCB = (NN + 1023) >> 10;   // scan blocks (98)

__device__ __forceinline__ float bf2f(unsigned short u) {
    return __uint_as_float(((unsigned int)u) << 16);
}

// ---- CSR build ------------------------------------------------------------

__global__ void k_deg(const int* __restrict__ dst, int* __restrict__ deg) {
    int i = blockIdx.x * blockDim.x + threadIdx.x;
    if (i < ET) {
        int d = (i < NE) ? dst[i] : (i - NE);
        atomicAdd(&deg[d], 1);
    }
}

__global__ __launch_bounds__(1024) void k_scan1(const int* __restrict__ deg,
                                                int* __restrict__ rp,
                                                int* __restrict__ bsum) {
    __shared__ int sm[1024];
    int t = threadIdx.x, b = blockIdx.x;
    int i = (b << 10) + t;
    int v = (i < NN) ? deg[i] : 0;
    sm[t] = v;
    __syncthreads();
    for (int off = 1; off < 1024; off <<= 1) {
        int u = (t >= off) ? sm[t - off] : 0;
        __syncthreads();
        sm[t] += u;
        __syncthreads();
    }
    if (i < NN) rp[i + 1] = sm[t];      // block-local inclusive scan
    if (t == 1023) bsum[b] = sm[1023];
}

__global__ __launch_bounds__(128) void k_scan2(const int* __restrict__ bsum,
                                               int* __restrict__ boff) {
    __shared__ int sm[128];
    int t = threadIdx.x;
    int v = (t < NSCB) ? bsum[t] : 0;
    sm[t] = v;
    __syncthreads();
    for (int off = 1; off < 128; off <<= 1) {
        int u = (t >= off) ? sm[t - off] : 0;
        __syncthreads();
        sm[t] += u;
        __syncthreads();
    }
    if (t < NSCB) boff[t] = sm[t] - v;  // exclusive
}

__global__ void k_scan3(int* __restrict__ rp, const int* __restrict__ boff,
                        int* __restrict__ cursor) {
    int i = blockIdx.x * blockDim.x + threadIdx.x;
    if (i < NN) {
        int val = rp[i + 1] + boff[i >> 10];
        rp[i + 1] = val;
        if (i + 1 < NN) cursor[i + 1] = val;
        if (i == 0) { rp[0] = 0; cursor[0] = 0; }
    }
}

__global__ void k_scatter(const int* __restrict__ src, const int* __restrict__ dst,
                          int* __restrict__ cursor, int* __restrict__ csr_src) {
    int i = blockIdx.x * blockDim.x + threadIdx.x;
    if (i < ET) {
        int s, d;
        if (i < NE) { s = src[i]; d = dst[i]; } else { s = d = i - NE; }
        int pos = atomicAdd(&cursor[d], 1);
        csr_src[pos] = s;
    }
}

// ---- GEMM: xp = h @ W (fp32 SIMT) + fused dots + bf16 xp output -----------

__global__ __launch_bounds__(256) void k_gemm(const float* __restrict__ A,
                                              const float* __restrict__ W,
                                              const float* __restrict__ a_s,
                                              const float* __restrict__ a_d,
                                              unsigned short* __restrict__ xpb,
                                              float* __restrict__ s_node,
                                              float* __restrict__ d_node) {
    __shared__ float hs[64][33];
    __shared__ float ws[32][128];
    int tid = threadIdx.x;
    int ty = tid >> 4, tx = tid & 15;
    int row0 = blockIdx.x * 64;
    float acc[4][8];
#pragma unroll
    for (int i = 0; i < 4; ++i)
#pragma unroll
        for (int j = 0; j < 8; ++j) acc[i][j] = 0.f;

    for (int k0 = 0; k0 < 128; k0 += 32) {
        {   // stage A tile: 64 rows x 32 k
            int r = tid >> 2;
            int cc = (tid & 3) << 3;
            int row = row0 + r;
            float4 v0 = make_float4(0.f, 0.f, 0.f, 0.f), v1 = v0;
            if (row < NN) {
                const float4* p = (const float4*)(A + (size_t)row * DH + k0 + cc);
                v0 = p[0]; v1 = p[1];
            }
            hs[r][cc + 0] = v0.x; hs[r][cc + 1] = v0.y;
            hs[r][cc + 2] = v0.z; hs[r][cc + 3] = v0.w;
            hs[r][cc + 4] = v1.x; hs[r][cc + 5] = v1.y;
            hs[r][cc + 6] = v1.z; hs[r][cc + 7] = v1.w;
        }
        {   // stage W tile: 32 k x 128 cols
            int r = tid >> 3;
            int cc = (tid & 7) << 4;
            const float4* p = (const float4*)(W + (size_t)(k0 + r) * DH + cc);
            float4* q = (float4*)&ws[r][cc];
            q[0] = p[0]; q[1] = p[1]; q[2] = p[2]; q[3] = p[3];
        }
        __syncthreads();
#pragma unroll
        for (int k = 0; k < 32; ++k) {
            float aa[4];
#pragma unroll
            for (int i = 0; i < 4; ++i) aa[i] = hs[ty * 4 + i][k];
            const float4 b0 = *(const float4*)&ws[k][tx * 8];
            const float4 b1 = *(const float4*)&ws[k][tx * 8 + 4];
            float bb[8] = {b0.x, b0.y, b0.z, b0.w, b1.x, b1.y, b1.z, b1.w};
#pragma unroll
            for (int i = 0; i < 4; ++i)
#pragma unroll
                for (int j = 0; j < 8; ++j)
                    acc[i][j] = fmaf(aa[i], bb[j], acc[i][j]);
        }
        __syncthreads();
    }

    // attention-vector slices for this thread's 8 columns
    float4 as0 = *(const float4*)(a_s + tx * 8);
    float4 as1 = *(const float4*)(a_s + tx * 8 + 4);
    float4 ad0 = *(const float4*)(a_d + tx * 8);
    float4 ad1 = *(const float4*)(a_d + tx * 8 + 4);
    float asv[8] = {as0.x, as0.y, as0.z, as0.w, as1.x, as1.y, as1.z, as1.w};
    float adv[8] = {ad0.x, ad0.y, ad0.z, ad0.w, ad1.x, ad1.y, ad1.z, ad1.w};

#pragma unroll
    for (int i = 0; i < 4; ++i) {
        int row = row0 + ty * 4 + i;
        if (row >= NN) continue;
        // bf16 xp write
        alignas(16) __hip_bfloat16 tmp[8];
#pragma unroll
        for (int j = 0; j < 8; ++j) tmp[j] = __float2bfloat16(acc[i][j]);
        *(uint4*)(xpb + (size_t)row * DH + tx * 8) = *(const uint4*)tmp;
        // fused dots: reduce across the 16 tx lanes (same ty -> same 16-lane group)
        float ps = 0.f, pd = 0.f;
#pragma unroll
        for (int j = 0; j < 8; ++j) {
            ps = fmaf(acc[i][j], asv[j], ps);
            pd = fmaf(acc[i][j], adv[j], pd);
        }
#pragma unroll
        for (int off = 8; off >= 1; off >>= 1) {
            ps += __shfl_xor(ps, off, 64);
            pd += __shfl_xor(pd, off, 64);
        }
        if (tx == 0) { s_node[row] = ps; d_node[row] = pd; }
    }
}

// ---- aggregation: wave per dst node; bf16 gather; fused bias/ReLU/BN ------

__global__ __launch_bounds__(256) void k_aggr(const unsigned short* __restrict__ xpb,
                                              const float* __restrict__ s_node,
                                              const float* __restrict__ d_node,
                                              const int* __restrict__ row_ptr,
                                              const int* __restrict__ csr_src,
                                              const float* __restrict__ bias,
                                              const float* __restrict__ gamma,
                                              const float* __restrict__ beta,
                                              const float* __restrict__ mean,
                                              const float* __restrict__ var,
                                              float* __restrict__ hout) {
    int wid = threadIdx.x >> 6, lane = threadIdx.x & 63;
    int n = blockIdx.x * 4 + wid;
    if (n >= NN) return;
    int s0 = row_ptr[n], s1 = row_ptr[n + 1];
    float dn = d_node[n];
    // pass 1: segment max (lane-parallel over edges)
    float mx = -1e30f;
    for (int j = s0 + lane; j < s1; j += 64) {
        int s = csr_src[j];
        float e = s_node[s] + dn;
        e = (e >= 0.f) ? e : 0.2f * e;
        mx = fmaxf(mx, e);
    }
#pragma unroll
    for (int off = 32; off >= 1; off >>= 1)
        mx = fmaxf(mx, __shfl_xor(mx, off, 64));
    // pass 2: whole wave per edge, coalesced 256B bf16 row gather
    float2 acc = make_float2(0.f, 0.f);
    float denom = 0.f;
    for (int j = s0; j < s1; ++j) {
        int s = csr_src[j];          // wave-uniform -> broadcast
        float e = s_node[s] + dn;
        e = (e >= 0.f) ? e : 0.2f * e;
        float w = __expf(e - mx);
        denom += w;
        ushort2 v = ((const ushort2*)(xpb + (size_t)s * DH))[lane];
        acc.x = fmaf(w, bf2f(v.x), acc.x);
        acc.y = fmaf(w, bf2f(v.y), acc.y);
    }
    float inv = 1.f / denom;         // denom >= 1 (self-loop term)
    int c0 = lane * 2, c1 = c0 + 1;
    float o0 = acc.x * inv + bias[c0];
    float o1 = acc.y * inv + bias[c1];
    o0 = fmaxf(o0, 0.f);
    o1 = fmaxf(o1, 0.f);
    o0 = (o0 - mean[c0]) * (gamma[c0] * rsqrtf(var[c0] + 1e-5f)) + beta[c0];
    o1 = (o1 - mean[c1]) * (gamma[c1] * rsqrtf(var[c1] + 1e-5f)) + beta[c1];
    ((float2*)(hout + (size_t)n * DH))[lane] = make_float2(o0, o1);
}

// ---- mean pool over sorted batch + final linear ---------------------------

__global__ __launch_bounds__(128) void k_pool1(const float* __restrict__ h,
                                               const int* __restrict__ batch,
                                               float* __restrict__ sums,
                                               int* __restrict__ cnts) {
    int c = threadIdx.x;
    int n0 = blockIdx.x * 64;
    int n1 = min(NN, n0 + 64);
    if (n0 >= NN) return;
    float acc = 0.f;
    int cur = batch[n0];
    int cnt = 0;
    for (int n = n0; n < n1; ++n) {
        int g = batch[n];
        if (g != cur) {
            atomicAdd(&sums[cur * DH + c], acc);
            if (c == 0) atomicAdd(&cnts[cur], cnt);
            acc = 0.f; cnt = 0; cur = g;
        }
        acc += h[(size_t)n * DH + c];
        ++cnt;
    }
    atomicAdd(&sums[cur * DH + c], acc);
    if (c == 0) atomicAdd(&cnts[cur], cnt);
}

__global__ __launch_bounds__(128) void k_pool2(const float* __restrict__ sums,
                                               const int* __restrict__ cnts,
                                               const float* __restrict__ lin_w,
                                               const float* __restrict__ lin_b,
                                               float* __restrict__ out) {
    __shared__ float sm[128];
    int g = blockIdx.x, c = threadIdx.x;
    float cnt = fmaxf((float)cnts[g], 1.f);
    sm[c] = (sums[g * DH + c] / cnt) * lin_w[c];
    __syncthreads();
    for (int off = 64; off >= 1; off >>= 1) {
        if (c < off) sm[c] += sm[c + off];
        __syncthreads();
    }
    if (c == 0) out[g] = sm[0] + lin_b[0];
}

// ---- launch ---------------------------------------------------------------

extern "C" void kernel_launch(void* const* d_in, const int* in_sizes, int n_in,
                              void* d_out, int out_size, void* d_ws, size_t ws_size,
                              hipStream_t stream) {
    const float* x     = (const float*)d_in[0];
    const int*   ei    = (const int*)d_in[1];
    const int*   batch = (const int*)d_in[2];
    const float* W     = (const float*)d_in[3];
    const float* a_src = (const float*)d_in[4];
    const float* a_dst = (const float*)d_in[5];
    const float* b     = (const float*)d_in[6];
    const float* bn_g  = (const float*)d_in[7];
    const float* bn_b  = (const float*)d_in[8];
    const float* bn_m  = (const float*)d_in[9];
    const float* bn_v  = (const float*)d_in[10];
    const float* lin_w = (const float*)d_in[11];
    const float* lin_b = (const float*)d_in[12];
    float* out = (float*)d_out;

    const int* srcp = ei;
    const int* dstp = ei + NE;

    char* wsp = (char*)d_ws;
    size_t off = 0;
    auto alloc = [&](size_t bytes) -> void* {
        void* p = wsp + off;
        off = (off + bytes + 511) & ~((size_t)511);
        return p;
    };
    unsigned short* xpb = (unsigned short*)alloc((size_t)NN * DH * 2);  // bf16 xp
    float* buf1    = (float*)alloc((size_t)NN * DH * 4);                // h
    float* s_node  = (float*)alloc((size_t)NN * 4);
    float* d_node  = (float*)alloc((size_t)NN * 4);
    int*   row_ptr = (int*)alloc((size_t)(NN + 1) * 4);
    int*   cursor  = (int*)alloc((size_t)NN * 4);          // also deg
    int*   csr_src = (int*)alloc((size_t)ET * 4);
    int*   bsum    = (int*)alloc((size_t)NSCB * 4);
    int*   boff    = (int*)alloc((size_t)NSCB * 4);
    float* sums    = (float*)alloc((size_t)NG * DH * 4);
    int*   cnts    = (int*)alloc((size_t)NG * 4);

    // CSR build (reused across the 5 layers)
    hipMemsetAsync(cursor, 0, (size_t)NN * 4, stream);
    k_deg<<<(ET + 255) / 256, 256, 0, stream>>>(dstp, cursor);
    k_scan1<<<NSCB, 1024, 0, stream>>>(cursor, row_ptr, bsum);
    k_scan2<<<1, 128, 0, stream>>>(bsum, boff);
    k_scan3<<<(NN + 255) / 256, 256, 0, stream>>>(row_ptr, boff, cursor);
    k_scatter<<<(ET + 255) / 256, 256, 0, stream>>>(srcp, dstp, cursor, csr_src);

    for (int l = 0; l < NL; ++l) {
        const float* hin = (l == 0) ? x : buf1;
        k_gemm<<<(NN + 63) / 64, 256, 0, stream>>>(hin, W + (size_t)l * DH * DH,
                                                   a_src + l * DH, a_dst + l * DH,
                                                   xpb, s_node, d_node);
        k_aggr<<<(NN + 3) / 4, 256, 0, stream>>>(xpb, s_node, d_node, row_ptr, csr_src,
                                                 b + l * DH, bn_g + l * DH, bn_b + l * DH,
                                                 bn_m + l * DH, bn_v + l * DH, buf1);
    }

    hipMemsetAsync(sums, 0, (size_t)NG * DH * 4, stream);
    hipMemsetAsync(cnts, 0, (size_t)NG * 4, stream);
    k_pool1<<<(NN + 63) / 64, 128, 0, stream>>>(buf1, batch, sums, cnts);
    k_pool2<<<NG, 128, 0, stream>>>(sums, cnts, lin_w, lin_b, out);
}

// Round 3
// 895.899 us; speedup vs baseline: 1.9191x; 1.5941x over previous
//
#include <hip/hip_runtime.h>
#include <hip/hip_bf16.h>
#include <math.h>

// simple_GAT: 5-layer GAT (heads=1) + BN(eval) + mean-pool + linear.
// R3: k_aggr restructured to kill the per-edge dependent-load chain:
// lane-parallel prefetch of edge indices + scores into registers, w=exp and
// denom computed lane-parallel, (w,src) staged in LDS, gather loop has only
// independent 256B row gathers -> deep vmcnt pipelining.

#define NN 100000
#define NE 1600000
#define DH 128
#define NL 5
#define NG 64

static constexpr int ET = NE + NN;      // edges + self loops
static constexpr int NSCB = (NN + 1023) >> 10;   // scan blocks (98)

__device__ __forceinline__ float bf2f(unsigned short u) {
    return __uint_as_float(((unsigned int)u) << 16);
}

// ---- CSR build ------------------------------------------------------------

__global__ void k_deg(const int* __restrict__ dst, int* __restrict__ deg) {
    int i = blockIdx.x * blockDim.x + threadIdx.x;
    if (i < ET) {
        int d = (i < NE) ? dst[i] : (i - NE);
        atomicAdd(&deg[d], 1);
    }
}

__global__ __launch_bounds__(1024) void k_scan1(const int* __restrict__ deg,
                                                int* __restrict__ rp,
                                                int* __restrict__ bsum) {
    __shared__ int sm[1024];
    int t = threadIdx.x, b = blockIdx.x;
    int i = (b << 10) + t;
    int v = (i < NN) ? deg[i] : 0;
    sm[t] = v;
    __syncthreads();
    for (int off = 1; off < 1024; off <<= 1) {
        int u = (t >= off) ? sm[t - off] : 0;
        __syncthreads();
        sm[t] += u;
        __syncthreads();
    }
    if (i < NN) rp[i + 1] = sm[t];      // block-local inclusive scan
    if (t == 1023) bsum[b] = sm[1023];
}

__global__ __launch_bounds__(128) void k_scan2(const int* __restrict__ bsum,
                                               int* __restrict__ boff) {
    __shared__ int sm[128];
    int t = threadIdx.x;
    int v = (t < NSCB) ? bsum[t] : 0;
    sm[t] = v;
    __syncthreads();
    for (int off = 1; off < 128; off <<= 1) {
        int u = (t >= off) ? sm[t - off] : 0;
        __syncthreads();
        sm[t] += u;
        __syncthreads();
    }
    if (t < NSCB) boff[t] = sm[t] - v;  // exclusive
}

__global__ void k_scan3(int* __restrict__ rp, const int* __restrict__ boff,
                        int* __restrict__ cursor) {
    int i = blockIdx.x * blockDim.x + threadIdx.x;
    if (i < NN) {
        int val = rp[i + 1] + boff[i >> 10];
        rp[i + 1] = val;
        if (i + 1 < NN) cursor[i + 1] = val;
        if (i == 0) { rp[0] = 0; cursor[0] = 0; }
    }
}

__global__ void k_scatter(const int* __restrict__ src, const int* __restrict__ dst,
                          int* __restrict__ cursor, int* __restrict__ csr_src) {
    int i = blockIdx.x * blockDim.x + threadIdx.x;
    if (i < ET) {
        int s, d;
        if (i < NE) { s = src[i]; d = dst[i]; } else { s = d = i - NE; }
        int pos = atomicAdd(&cursor[d], 1);
        csr_src[pos] = s;
    }
}

// ---- GEMM: xp = h @ W (fp32 SIMT) + fused dots + bf16 xp output -----------

__global__ __launch_bounds__(256) void k_gemm(const float* __restrict__ A,
                                              const float* __restrict__ W,
                                              const float* __restrict__ a_s,
                                              const float* __restrict__ a_d,
                                              unsigned short* __restrict__ xpb,
                                              float* __restrict__ s_node,
                                              float* __restrict__ d_node) {
    __shared__ float hs[64][33];
    __shared__ float ws[32][128];
    int tid = threadIdx.x;
    int ty = tid >> 4, tx = tid & 15;
    int row0 = blockIdx.x * 64;
    float acc[4][8];
#pragma unroll
    for (int i = 0; i < 4; ++i)
#pragma unroll
        for (int j = 0; j < 8; ++j) acc[i][j] = 0.f;

    for (int k0 = 0; k0 < 128; k0 += 32) {
        {   // stage A tile: 64 rows x 32 k
            int r = tid >> 2;
            int cc = (tid & 3) << 3;
            int row = row0 + r;
            float4 v0 = make_float4(0.f, 0.f, 0.f, 0.f), v1 = v0;
            if (row < NN) {
                const float4* p = (const float4*)(A + (size_t)row * DH + k0 + cc);
                v0 = p[0]; v1 = p[1];
            }
            hs[r][cc + 0] = v0.x; hs[r][cc + 1] = v0.y;
            hs[r][cc + 2] = v0.z; hs[r][cc + 3] = v0.w;
            hs[r][cc + 4] = v1.x; hs[r][cc + 5] = v1.y;
            hs[r][cc + 6] = v1.z; hs[r][cc + 7] = v1.w;
        }
        {   // stage W tile: 32 k x 128 cols
            int r = tid >> 3;
            int cc = (tid & 7) << 4;
            const float4* p = (const float4*)(W + (size_t)(k0 + r) * DH + cc);
            float4* q = (float4*)&ws[r][cc];
            q[0] = p[0]; q[1] = p[1]; q[2] = p[2]; q[3] = p[3];
        }
        __syncthreads();
#pragma unroll
        for (int k = 0; k < 32; ++k) {
            float aa[4];
#pragma unroll
            for (int i = 0; i < 4; ++i) aa[i] = hs[ty * 4 + i][k];
            const float4 b0 = *(const float4*)&ws[k][tx * 8];
            const float4 b1 = *(const float4*)&ws[k][tx * 8 + 4];
            float bb[8] = {b0.x, b0.y, b0.z, b0.w, b1.x, b1.y, b1.z, b1.w};
#pragma unroll
            for (int i = 0; i < 4; ++i)
#pragma unroll
                for (int j = 0; j < 8; ++j)
                    acc[i][j] = fmaf(aa[i], bb[j], acc[i][j]);
        }
        __syncthreads();
    }

    // attention-vector slices for this thread's 8 columns
    float4 as0 = *(const float4*)(a_s + tx * 8);
    float4 as1 = *(const float4*)(a_s + tx * 8 + 4);
    float4 ad0 = *(const float4*)(a_d + tx * 8);
    float4 ad1 = *(const float4*)(a_d + tx * 8 + 4);
    float asv[8] = {as0.x, as0.y, as0.z, as0.w, as1.x, as1.y, as1.z, as1.w};
    float adv[8] = {ad0.x, ad0.y, ad0.z, ad0.w, ad1.x, ad1.y, ad1.z, ad1.w};

#pragma unroll
    for (int i = 0; i < 4; ++i) {
        int row = row0 + ty * 4 + i;
        if (row >= NN) continue;
        // bf16 xp write
        alignas(16) __hip_bfloat16 tmp[8];
#pragma unroll
        for (int j = 0; j < 8; ++j) tmp[j] = __float2bfloat16(acc[i][j]);
        *(uint4*)(xpb + (size_t)row * DH + tx * 8) = *(const uint4*)tmp;
        // fused dots: reduce across the 16 tx lanes (same ty -> same 16-lane group)
        float ps = 0.f, pd = 0.f;
#pragma unroll
        for (int j = 0; j < 8; ++j) {
            ps = fmaf(acc[i][j], asv[j], ps);
            pd = fmaf(acc[i][j], adv[j], pd);
        }
#pragma unroll
        for (int off = 8; off >= 1; off >>= 1) {
            ps += __shfl_xor(ps, off, 64);
            pd += __shfl_xor(pd, off, 64);
        }
        if (tx == 0) { s_node[row] = ps; d_node[row] = pd; }
    }
}

// ---- aggregation: wave per dst node; register-prefetched edges ------------

__global__ __launch_bounds__(256) void k_aggr(const unsigned short* __restrict__ xpb,
                                              const float* __restrict__ s_node,
                                              const float* __restrict__ d_node,
                                              const int* __restrict__ row_ptr,
                                              const int* __restrict__ csr_src,
                                              const float* __restrict__ bias,
                                              const float* __restrict__ gamma,
                                              const float* __restrict__ beta,
                                              const float* __restrict__ mean,
                                              const float* __restrict__ var,
                                              float* __restrict__ hout) {
    __shared__ float2 stash[4][128];
    int wid = threadIdx.x >> 6, lane = threadIdx.x & 63;
    int n = blockIdx.x * 4 + wid;
    if (n >= NN) return;
    int s0 = row_ptr[n], s1 = row_ptr[n + 1];
    int deg = s1 - s0;
    float dn = d_node[n];

    // lane-parallel: up to 128 edges -> registers (deg>128 handled in tail)
    int   sidx[2];
    float ev[2];
#pragma unroll
    for (int k = 0; k < 2; ++k) {
        int j = s0 + k * 64 + lane;
        int s = 0;
        float e = -1e30f;
        if (j < s1) {
            s = csr_src[j];
            float t = s_node[s] + dn;
            e = (t >= 0.f) ? t : 0.2f * t;
        }
        sidx[k] = s;
        ev[k] = e;
    }
    float mx = fmaxf(ev[0], ev[1]);
    for (int j = s0 + 128 + lane; j < s1; j += 64) {   // never in practice
        int s = csr_src[j];
        float t = s_node[s] + dn;
        t = (t >= 0.f) ? t : 0.2f * t;
        mx = fmaxf(mx, t);
    }
#pragma unroll
    for (int off = 32; off >= 1; off >>= 1)
        mx = fmaxf(mx, __shfl_xor(mx, off, 64));

    // lane-parallel weights + denom
    float w0 = (ev[0] > -1e29f) ? __expf(ev[0] - mx) : 0.f;
    float w1 = (ev[1] > -1e29f) ? __expf(ev[1] - mx) : 0.f;
    float denom = w0 + w1;
#pragma unroll
    for (int off = 32; off >= 1; off >>= 1)
        denom += __shfl_xor(denom, off, 64);

    // stage (w, src) pairs in LDS for broadcast reads
    stash[wid][lane]      = make_float2(w0, __int_as_float(sidx[0]));
    stash[wid][64 + lane] = make_float2(w1, __int_as_float(sidx[1]));

    // gather loop: only independent 256B row gathers
    float2 acc = make_float2(0.f, 0.f);
    int cnt = min(deg, 128);
#pragma unroll 4
    for (int jj = 0; jj < cnt; ++jj) {
        float2 p = stash[wid][jj];
        float w = p.x;
        int   s = __float_as_int(p.y);
        ushort2 v = ((const ushort2*)xpb)[((size_t)s << 6) + lane];
        acc.x = fmaf(w, bf2f(v.x), acc.x);
        acc.y = fmaf(w, bf2f(v.y), acc.y);
    }
    // tail fallback for deg>128 (statistically never; kept for correctness)
    for (int j = s0 + 128; j < s1; ++j) {
        int s = csr_src[j];
        float t = s_node[s] + dn;
        t = (t >= 0.f) ? t : 0.2f * t;
        float w = __expf(t - mx);
        denom += w;
        ushort2 v = ((const ushort2*)xpb)[((size_t)s << 6) + lane];
        acc.x = fmaf(w, bf2f(v.x), acc.x);
        acc.y = fmaf(w, bf2f(v.y), acc.y);
    }

    float inv = 1.f / denom;         // denom >= 1 (self-loop term)
    int c0 = lane * 2, c1 = c0 + 1;
    float o0 = acc.x * inv + bias[c0];
    float o1 = acc.y * inv + bias[c1];
    o0 = fmaxf(o0, 0.f);
    o1 = fmaxf(o1, 0.f);
    o0 = (o0 - mean[c0]) * (gamma[c0] * rsqrtf(var[c0] + 1e-5f)) + beta[c0];
    o1 = (o1 - mean[c1]) * (gamma[c1] * rsqrtf(var[c1] + 1e-5f)) + beta[c1];
    ((float2*)(hout + (size_t)n * DH))[lane] = make_float2(o0, o1);
}

// ---- mean pool over sorted batch + final linear ---------------------------

__global__ __launch_bounds__(128) void k_pool1(const float* __restrict__ h,
                                               const int* __restrict__ batch,
                                               float* __restrict__ sums,
                                               int* __restrict__ cnts) {
    int c = threadIdx.x;
    int n0 = blockIdx.x * 64;
    int n1 = min(NN, n0 + 64);
    if (n0 >= NN) return;
    float acc = 0.f;
    int cur = batch[n0];
    int cnt = 0;
    for (int n = n0; n < n1; ++n) {
        int g = batch[n];
        if (g != cur) {
            atomicAdd(&sums[cur * DH + c], acc);
            if (c == 0) atomicAdd(&cnts[cur], cnt);
            acc = 0.f; cnt = 0; cur = g;
        }
        acc += h[(size_t)n * DH + c];
        ++cnt;
    }
    atomicAdd(&sums[cur * DH + c], acc);
    if (c == 0) atomicAdd(&cnts[cur], cnt);
}

__global__ __launch_bounds__(128) void k_pool2(const float* __restrict__ sums,
                                               const int* __restrict__ cnts,
                                               const float* __restrict__ lin_w,
                                               const float* __restrict__ lin_b,
                                               float* __restrict__ out) {
    __shared__ float sm[128];
    int g = blockIdx.x, c = threadIdx.x;
    float cnt = fmaxf((float)cnts[g], 1.f);
    sm[c] = (sums[g * DH + c] / cnt) * lin_w[c];
    __syncthreads();
    for (int off = 64; off >= 1; off >>= 1) {
        if (c < off) sm[c] += sm[c + off];
        __syncthreads();
    }
    if (c == 0) out[g] = sm[0] + lin_b[0];
}

// ---- launch ---------------------------------------------------------------

extern "C" void kernel_launch(void* const* d_in, const int* in_sizes, int n_in,
                              void* d_out, int out_size, void* d_ws, size_t ws_size,
                              hipStream_t stream) {
    const float* x     = (const float*)d_in[0];
    const int*   ei    = (const int*)d_in[1];
    const int*   batch = (const int*)d_in[2];
    const float* W     = (const float*)d_in[3];
    const float* a_src = (const float*)d_in[4];
    const float* a_dst = (const float*)d_in[5];
    const float* b     = (const float*)d_in[6];
    const float* bn_g  = (const float*)d_in[7];
    const float* bn_b  = (const float*)d_in[8];
    const float* bn_m  = (const float*)d_in[9];
    const float* bn_v  = (const float*)d_in[10];
    const float* lin_w = (const float*)d_in[11];
    const float* lin_b = (const float*)d_in[12];
    float* out = (float*)d_out;

    const int* srcp = ei;
    const int* dstp = ei + NE;

    char* wsp = (char*)d_ws;
    size_t off = 0;
    auto alloc = [&](size_t bytes) -> void* {
        void* p = wsp + off;
        off = (off + bytes + 511) & ~((size_t)511);
        return p;
    };
    unsigned short* xpb = (unsigned short*)alloc((size_t)NN * DH * 2);  // bf16 xp
    float* buf1    = (float*)alloc((size_t)NN * DH * 4);                // h
    float* s_node  = (float*)alloc((size_t)NN * 4);
    float* d_node  = (float*)alloc((size_t)NN * 4);
    int*   row_ptr = (int*)alloc((size_t)(NN + 1) * 4);
    int*   cursor  = (int*)alloc((size_t)NN * 4);          // also deg
    int*   csr_src = (int*)alloc((size_t)ET * 4);
    int*   bsum    = (int*)alloc((size_t)NSCB * 4);
    int*   boff    = (int*)alloc((size_t)NSCB * 4);
    float* sums    = (float*)alloc((size_t)NG * DH * 4);
    int*   cnts    = (int*)alloc((size_t)NG * 4);

    // CSR build (reused across the 5 layers)
    hipMemsetAsync(cursor, 0, (size_t)NN * 4, stream);
    k_deg<<<(ET + 255) / 256, 256, 0, stream>>>(dstp, cursor);
    k_scan1<<<NSCB, 1024, 0, stream>>>(cursor, row_ptr, bsum);
    k_scan2<<<1, 128, 0, stream>>>(bsum, boff);
    k_scan3<<<(NN + 255) / 256, 256, 0, stream>>>(row_ptr, boff, cursor);
    k_scatter<<<(ET + 255) / 256, 256, 0, stream>>>(srcp, dstp, cursor, csr_src);

    for (int l = 0; l < NL; ++l) {
        const float* hin = (l == 0) ? x : buf1;
        k_gemm<<<(NN + 63) / 64, 256, 0, stream>>>(hin, W + (size_t)l * DH * DH,
                                                   a_src + l * DH, a_dst + l * DH,
                                                   xpb, s_node, d_node);
        k_aggr<<<(NN + 3) / 4, 256, 0, stream>>>(xpb, s_node, d_node, row_ptr, csr_src,
                                                 b + l * DH, bn_g + l * DH, bn_b + l * DH,
                                                 bn_m + l * DH, bn_v + l * DH, buf1);
    }

    hipMemsetAsync(sums, 0, (size_t)NG * DH * 4, stream);
    hipMemsetAsync(cnts, 0, (size_t)NG * 4, stream);
    k_pool1<<<(NN + 63) / 64, 128, 0, stream>>>(buf1, batch, sums, cnts);
    k_pool2<<<NG, 128, 0, stream>>>(sums, cnts, lin_w, lin_b, out);
}

// Round 4
// 743.940 us; speedup vs baseline: 2.3111x; 1.2043x over previous
//
#include <hip/hip_runtime.h>
#include <hip/hip_bf16.h>
#include <math.h>

// simple_GAT: 5-layer GAT (heads=1) + BN(eval) + mean-pool + linear.
// R4: CSR build rebuilt as two-level bucket partition (391 buckets x 256 dst
// nodes): LDS-aggregated histogram -> tiny scan -> chunk-reserved pair
// scatter (coalesced writes) -> per-bucket finalize that derives row_ptr via
// LDS scan (kills k_deg + global 100K scan) and scatters csr_src into an
// L2-hot 17KB window. Fixes the 108MB write amplification seen in R3.

#define NN 100000
#define NE 1600000
#define DH 128
#define NL 5
#define NG 64

static constexpr int ET = NE + NN;            // edges + self loops
static constexpr int NBK = (NN + 255) >> 8;   // 391 buckets of 256 dst nodes

__device__ __forceinline__ float bf2f(unsigned short u) {
    return __uint_as_float(((unsigned int)u) << 16);
}

// ---- CSR build (bucketed) -------------------------------------------------

__global__ __launch_bounds__(256) void k_bcount(const int* __restrict__ dst,
                                                int* __restrict__ bcnt) {
    __shared__ int h[NBK];
    for (int i = threadIdx.x; i < NBK; i += 256) h[i] = 0;
    __syncthreads();
    int base = blockIdx.x * 4096;
#pragma unroll
    for (int k = 0; k < 16; ++k) {
        int i = base + k * 256 + threadIdx.x;
        if (i < ET) {
            int d = (i < NE) ? dst[i] : (i - NE);
            atomicAdd(&h[d >> 8], 1);
        }
    }
    __syncthreads();
    for (int i = threadIdx.x; i < NBK; i += 256)
        if (h[i]) atomicAdd(&bcnt[i], h[i]);
}

__global__ __launch_bounds__(512) void k_bscan(const int* __restrict__ bcnt,
                                               int* __restrict__ bbase,
                                               int* __restrict__ bcur,
                                               int* __restrict__ row_ptr) {
    __shared__ int sm[512];
    int t = threadIdx.x;
    int v = (t < NBK) ? bcnt[t] : 0;
    sm[t] = v;
    __syncthreads();
    for (int off = 1; off < 512; off <<= 1) {
        int u = (t >= off) ? sm[t - off] : 0;
        __syncthreads();
        sm[t] += u;
        __syncthreads();
    }
    if (t < NBK) { bbase[t] = sm[t] - v; bcur[t] = sm[t] - v; }
    if (t == 0) { bbase[NBK] = ET; row_ptr[NN] = ET; }
}

__global__ __launch_bounds__(512) void k_bscatter(const int* __restrict__ src,
                                                  const int* __restrict__ dst,
                                                  int* __restrict__ bcur,
                                                  int2* __restrict__ pairs) {
    __shared__ int lcnt[NBK];
    __shared__ int lbase[NBK];
    for (int i = threadIdx.x; i < NBK; i += 512) lcnt[i] = 0;
    __syncthreads();
    int base = blockIdx.x * 4096;
    int es[8], ed[8], er[8];
#pragma unroll
    for (int k = 0; k < 8; ++k) {
        int i = base + k * 512 + threadIdx.x;
        if (i < ET) {
            int s, d;
            if (i < NE) { s = src[i]; d = dst[i]; } else { s = d = i - NE; }
            es[k] = s; ed[k] = d;
            er[k] = atomicAdd(&lcnt[d >> 8], 1);
        } else {
            ed[k] = -1;
        }
    }
    __syncthreads();
    for (int i = threadIdx.x; i < NBK; i += 512)
        lbase[i] = lcnt[i] ? atomicAdd(&bcur[i], lcnt[i]) : 0;
    __syncthreads();
#pragma unroll
    for (int k = 0; k < 8; ++k) {
        if (ed[k] >= 0) {
            int bk = ed[k] >> 8;
            pairs[lbase[bk] + er[k]] = make_int2(es[k], ed[k]);
        }
    }
}

__global__ __launch_bounds__(256) void k_bfinal(const int2* __restrict__ pairs,
                                                const int* __restrict__ bbase,
                                                int* __restrict__ row_ptr,
                                                int* __restrict__ csr_src) {
    __shared__ int ldeg[256];
    __shared__ int lcur[256];
    __shared__ int sm[256];
    int b = blockIdx.x, t = threadIdx.x;
    int n0 = b << 8;
    int e0 = bbase[b], e1 = bbase[b + 1];
    ldeg[t] = 0;
    __syncthreads();
    for (int j = e0 + t; j < e1; j += 256)
        atomicAdd(&ldeg[pairs[j].y - n0], 1);
    __syncthreads();
    int v = ldeg[t];
    sm[t] = v;
    __syncthreads();
    for (int off = 1; off < 256; off <<= 1) {
        int u = (t >= off) ? sm[t - off] : 0;
        __syncthreads();
        sm[t] += u;
        __syncthreads();
    }
    int excl = sm[t] - v;
    lcur[t] = excl;
    int n = n0 + t;
    if (n < NN) row_ptr[n] = e0 + excl;
    __syncthreads();
    for (int j = e0 + t; j < e1; j += 256) {
        int2 p = pairs[j];
        int local = atomicAdd(&lcur[p.y - n0], 1);
        csr_src[e0 + local] = p.x;
    }
}

// ---- GEMM: xp = h @ W (fp32 SIMT) + fused dots + bf16 xp output -----------

__global__ __launch_bounds__(256) void k_gemm(const float* __restrict__ A,
                                              const float* __restrict__ W,
                                              const float* __restrict__ a_s,
                                              const float* __restrict__ a_d,
                                              unsigned short* __restrict__ xpb,
                                              float* __restrict__ s_node,
                                              float* __restrict__ d_node) {
    __shared__ float hs[64][33];
    __shared__ float ws[32][128];
    int tid = threadIdx.x;
    int ty = tid >> 4, tx = tid & 15;
    int row0 = blockIdx.x * 64;
    float acc[4][8];
#pragma unroll
    for (int i = 0; i < 4; ++i)
#pragma unroll
        for (int j = 0; j < 8; ++j) acc[i][j] = 0.f;

    for (int k0 = 0; k0 < 128; k0 += 32) {
        {   // stage A tile: 64 rows x 32 k
            int r = tid >> 2;
            int cc = (tid & 3) << 3;
            int row = row0 + r;
            float4 v0 = make_float4(0.f, 0.f, 0.f, 0.f), v1 = v0;
            if (row < NN) {
                const float4* p = (const float4*)(A + (size_t)row * DH + k0 + cc);
                v0 = p[0]; v1 = p[1];
            }
            hs[r][cc + 0] = v0.x; hs[r][cc + 1] = v0.y;
            hs[r][cc + 2] = v0.z; hs[r][cc + 3] = v0.w;
            hs[r][cc + 4] = v1.x; hs[r][cc + 5] = v1.y;
            hs[r][cc + 6] = v1.z; hs[r][cc + 7] = v1.w;
        }
        {   // stage W tile: 32 k x 128 cols
            int r = tid >> 3;
            int cc = (tid & 7) << 4;
            const float4* p = (const float4*)(W + (size_t)(k0 + r) * DH + cc);
            float4* q = (float4*)&ws[r][cc];
            q[0] = p[0]; q[1] = p[1]; q[2] = p[2]; q[3] = p[3];
        }
        __syncthreads();
#pragma unroll
        for (int k = 0; k < 32; ++k) {
            float aa[4];
#pragma unroll
            for (int i = 0; i < 4; ++i) aa[i] = hs[ty * 4 + i][k];
            const float4 b0 = *(const float4*)&ws[k][tx * 8];
            const float4 b1 = *(const float4*)&ws[k][tx * 8 + 4];
            float bb[8] = {b0.x, b0.y, b0.z, b0.w, b1.x, b1.y, b1.z, b1.w};
#pragma unroll
            for (int i = 0; i < 4; ++i)
#pragma unroll
                for (int j = 0; j < 8; ++j)
                    acc[i][j] = fmaf(aa[i], bb[j], acc[i][j]);
        }
        __syncthreads();
    }

    // attention-vector slices for this thread's 8 columns
    float4 as0 = *(const float4*)(a_s + tx * 8);
    float4 as1 = *(const float4*)(a_s + tx * 8 + 4);
    float4 ad0 = *(const float4*)(a_d + tx * 8);
    float4 ad1 = *(const float4*)(a_d + tx * 8 + 4);
    float asv[8] = {as0.x, as0.y, as0.z, as0.w, as1.x, as1.y, as1.z, as1.w};
    float adv[8] = {ad0.x, ad0.y, ad0.z, ad0.w, ad1.x, ad1.y, ad1.z, ad1.w};

#pragma unroll
    for (int i = 0; i < 4; ++i) {
        int row = row0 + ty * 4 + i;
        if (row >= NN) continue;
        // bf16 xp write
        alignas(16) __hip_bfloat16 tmp[8];
#pragma unroll
        for (int j = 0; j < 8; ++j) tmp[j] = __float2bfloat16(acc[i][j]);
        *(uint4*)(xpb + (size_t)row * DH + tx * 8) = *(const uint4*)tmp;
        // fused dots: reduce across the 16 tx lanes (same ty -> same 16-lane group)
        float ps = 0.f, pd = 0.f;
#pragma unroll
        for (int j = 0; j < 8; ++j) {
            ps = fmaf(acc[i][j], asv[j], ps);
            pd = fmaf(acc[i][j], adv[j], pd);
        }
#pragma unroll
        for (int off = 8; off >= 1; off >>= 1) {
            ps += __shfl_xor(ps, off, 64);
            pd += __shfl_xor(pd, off, 64);
        }
        if (tx == 0) { s_node[row] = ps; d_node[row] = pd; }
    }
}

// ---- aggregation: wave per dst node; register-prefetched edges ------------

__global__ __launch_bounds__(256) void k_aggr(const unsigned short* __restrict__ xpb,
                                              const float* __restrict__ s_node,
                                              const float* __restrict__ d_node,
                                              const int* __restrict__ row_ptr,
                                              const int* __restrict__ csr_src,
                                              const float* __restrict__ bias,
                                              const float* __restrict__ gamma,
                                              const float* __restrict__ beta,
                                              const float* __restrict__ mean,
                                              const float* __restrict__ var,
                                              float* __restrict__ hout) {
    __shared__ float2 stash[4][128];
    int wid = threadIdx.x >> 6, lane = threadIdx.x & 63;
    int n = blockIdx.x * 4 + wid;
    if (n >= NN) return;
    int s0 = row_ptr[n], s1 = row_ptr[n + 1];
    int deg = s1 - s0;
    float dn = d_node[n];

    // lane-parallel: up to 128 edges -> registers (deg>128 handled in tail)
    int   sidx[2];
    float ev[2];
#pragma unroll
    for (int k = 0; k < 2; ++k) {
        int j = s0 + k * 64 + lane;
        int s = 0;
        float e = -1e30f;
        if (j < s1) {
            s = csr_src[j];
            float t = s_node[s] + dn;
            e = (t >= 0.f) ? t : 0.2f * t;
        }
        sidx[k] = s;
        ev[k] = e;
    }
    float mx = fmaxf(ev[0], ev[1]);
    for (int j = s0 + 128 + lane; j < s1; j += 64) {   // never in practice
        int s = csr_src[j];
        float t = s_node[s] + dn;
        t = (t >= 0.f) ? t : 0.2f * t;
        mx = fmaxf(mx, t);
    }
#pragma unroll
    for (int off = 32; off >= 1; off >>= 1)
        mx = fmaxf(mx, __shfl_xor(mx, off, 64));

    // lane-parallel weights + denom
    float w0 = (ev[0] > -1e29f) ? __expf(ev[0] - mx) : 0.f;
    float w1 = (ev[1] > -1e29f) ? __expf(ev[1] - mx) : 0.f;
    float denom = w0 + w1;
#pragma unroll
    for (int off = 32; off >= 1; off >>= 1)
        denom += __shfl_xor(denom, off, 64);

    // stage (w, src) pairs in LDS for broadcast reads
    stash[wid][lane]      = make_float2(w0, __int_as_float(sidx[0]));
    stash[wid][64 + lane] = make_float2(w1, __int_as_float(sidx[1]));

    // gather loop: only independent 256B row gathers
    float2 acc = make_float2(0.f, 0.f);
    int cnt = min(deg, 128);
#pragma unroll 4
    for (int jj = 0; jj < cnt; ++jj) {
        float2 p = stash[wid][jj];
        float w = p.x;
        int   s = __float_as_int(p.y);
        ushort2 v = ((const ushort2*)xpb)[((size_t)s << 6) + lane];
        acc.x = fmaf(w, bf2f(v.x), acc.x);
        acc.y = fmaf(w, bf2f(v.y), acc.y);
    }
    // tail fallback for deg>128 (statistically never; kept for correctness)
    for (int j = s0 + 128; j < s1; ++j) {
        int s = csr_src[j];
        float t = s_node[s] + dn;
        t = (t >= 0.f) ? t : 0.2f * t;
        float w = __expf(t - mx);
        denom += w;
        ushort2 v = ((const ushort2*)xpb)[((size_t)s << 6) + lane];
        acc.x = fmaf(w, bf2f(v.x), acc.x);
        acc.y = fmaf(w, bf2f(v.y), acc.y);
    }

    float inv = 1.f / denom;         // denom >= 1 (self-loop term)
    int c0 = lane * 2, c1 = c0 + 1;
    float o0 = acc.x * inv + bias[c0];
    float o1 = acc.y * inv + bias[c1];
    o0 = fmaxf(o0, 0.f);
    o1 = fmaxf(o1, 0.f);
    o0 = (o0 - mean[c0]) * (gamma[c0] * rsqrtf(var[c0] + 1e-5f)) + beta[c0];
    o1 = (o1 - mean[c1]) * (gamma[c1] * rsqrtf(var[c1] + 1e-5f)) + beta[c1];
    ((float2*)(hout + (size_t)n * DH))[lane] = make_float2(o0, o1);
}

// ---- mean pool over sorted batch + final linear ---------------------------

__global__ __launch_bounds__(128) void k_pool1(const float* __restrict__ h,
                                               const int* __restrict__ batch,
                                               float* __restrict__ sums,
                                               int* __restrict__ cnts) {
    int c = threadIdx.x;
    int n0 = blockIdx.x * 64;
    int n1 = min(NN, n0 + 64);
    if (n0 >= NN) return;
    float acc = 0.f;
    int cur = batch[n0];
    int cnt = 0;
    for (int n = n0; n < n1; ++n) {
        int g = batch[n];
        if (g != cur) {
            atomicAdd(&sums[cur * DH + c], acc);
            if (c == 0) atomicAdd(&cnts[cur], cnt);
            acc = 0.f; cnt = 0; cur = g;
        }
        acc += h[(size_t)n * DH + c];
        ++cnt;
    }
    atomicAdd(&sums[cur * DH + c], acc);
    if (c == 0) atomicAdd(&cnts[cur], cnt);
}

__global__ __launch_bounds__(128) void k_pool2(const float* __restrict__ sums,
                                               const int* __restrict__ cnts,
                                               const float* __restrict__ lin_w,
                                               const float* __restrict__ lin_b,
                                               float* __restrict__ out) {
    __shared__ float sm[128];
    int g = blockIdx.x, c = threadIdx.x;
    float cnt = fmaxf((float)cnts[g], 1.f);
    sm[c] = (sums[g * DH + c] / cnt) * lin_w[c];
    __syncthreads();
    for (int off = 64; off >= 1; off >>= 1) {
        if (c < off) sm[c] += sm[c + off];
        __syncthreads();
    }
    if (c == 0) out[g] = sm[0] + lin_b[0];
}

// ---- launch ---------------------------------------------------------------

extern "C" void kernel_launch(void* const* d_in, const int* in_sizes, int n_in,
                              void* d_out, int out_size, void* d_ws, size_t ws_size,
                              hipStream_t stream) {
    const float* x     = (const float*)d_in[0];
    const int*   ei    = (const int*)d_in[1];
    const int*   batch = (const int*)d_in[2];
    const float* W     = (const float*)d_in[3];
    const float* a_src = (const float*)d_in[4];
    const float* a_dst = (const float*)d_in[5];
    const float* b     = (const float*)d_in[6];
    const float* bn_g  = (const float*)d_in[7];
    const float* bn_b  = (const float*)d_in[8];
    const float* bn_m  = (const float*)d_in[9];
    const float* bn_v  = (const float*)d_in[10];
    const float* lin_w = (const float*)d_in[11];
    const float* lin_b = (const float*)d_in[12];
    float* out = (float*)d_out;

    const int* srcp = ei;
    const int* dstp = ei + NE;

    char* wsp = (char*)d_ws;
    size_t off = 0;
    auto alloc = [&](size_t bytes) -> void* {
        void* p = wsp + off;
        off = (off + bytes + 511) & ~((size_t)511);
        return p;
    };
    unsigned short* xpb = (unsigned short*)alloc((size_t)NN * DH * 2);  // bf16 xp
    float* buf1    = (float*)alloc((size_t)NN * DH * 4);                // h
    float* s_node  = (float*)alloc((size_t)NN * 4);
    float* d_node  = (float*)alloc((size_t)NN * 4);
    int*   row_ptr = (int*)alloc((size_t)(NN + 1) * 4);
    int*   csr_src = (int*)alloc((size_t)ET * 4);
    int2*  pairs   = (int2*)alloc((size_t)ET * 8);
    int*   bcnt    = (int*)alloc((size_t)NBK * 4);
    int*   bbase   = (int*)alloc((size_t)(NBK + 1) * 4);
    int*   bcur    = (int*)alloc((size_t)NBK * 4);
    float* sums    = (float*)alloc((size_t)NG * DH * 4);
    int*   cnts    = (int*)alloc((size_t)NG * 4);

    // CSR build (bucketed; reused across the 5 layers)
    hipMemsetAsync(bcnt, 0, (size_t)NBK * 4, stream);
    k_bcount<<<(ET + 4095) / 4096, 256, 0, stream>>>(dstp, bcnt);
    k_bscan<<<1, 512, 0, stream>>>(bcnt, bbase, bcur, row_ptr);
    k_bscatter<<<(ET + 4095) / 4096, 512, 0, stream>>>(srcp, dstp, bcur, pairs);
    k_bfinal<<<NBK, 256, 0, stream>>>(pairs, bbase, row_ptr, csr_src);

    for (int l = 0; l < NL; ++l) {
        const float* hin = (l == 0) ? x : buf1;
        k_gemm<<<(NN + 63) / 64, 256, 0, stream>>>(hin, W + (size_t)l * DH * DH,
                                                   a_src + l * DH, a_dst + l * DH,
                                                   xpb, s_node, d_node);
        k_aggr<<<(NN + 3) / 4, 256, 0, stream>>>(xpb, s_node, d_node, row_ptr, csr_src,
                                                 b + l * DH, bn_g + l * DH, bn_b + l * DH,
                                                 bn_m + l * DH, bn_v + l * DH, buf1);
    }

    hipMemsetAsync(sums, 0, (size_t)NG * DH * 4, stream);
    hipMemsetAsync(cnts, 0, (size_t)NG * 4, stream);
    k_pool1<<<(NN + 63) / 64, 128, 0, stream>>>(buf1, batch, sums, cnts);
    k_pool2<<<NG, 128, 0, stream>>>(sums, cnts, lin_w, lin_b, out);
}

// Round 5
// 559.574 us; speedup vs baseline: 3.0725x; 1.3295x over previous
//
#include <hip/hip_runtime.h>
#include <hip/hip_bf16.h>
#include <math.h>

// simple_GAT: 5-layer GAT (heads=1) + BN(eval) + mean-pool + linear.
// R5: GEMM converted to bf16 MFMA (16x16x32) with XOR-swizzled LDS B-tiles and
// fused dots + bf16 xp epilogue; h kept bf16 end-to-end; k_aggr processes two
// edges per wave-iteration (half-wave per edge, ushort4 gathers).

#define NN 100000
#define NE 1600000
#define DH 128
#define NL 5
#define NG 64

static constexpr int ET = NE + NN;            // edges + self loops
static constexpr int NBK = (NN + 255) >> 8;   // 391 buckets of 256 dst nodes

typedef __attribute__((ext_vector_type(8))) short bf16x8;
typedef __attribute__((ext_vector_type(4))) float f32x4;

__device__ __forceinline__ float bf2f(unsigned short u) {
    return __uint_as_float(((unsigned int)u) << 16);
}
__device__ __forceinline__ unsigned short f2bf(float v) {
    __hip_bfloat16 h = __float2bfloat16(v);
    return *reinterpret_cast<unsigned short*>(&h);
}

// ---- input prep: x -> bf16, W -> bf16 transposed --------------------------

__global__ __launch_bounds__(256) void k_castx(const float* __restrict__ x,
                                               unsigned short* __restrict__ xb) {
    int i = blockIdx.x * 2048 + threadIdx.x * 8;
    float4 v0 = *(const float4*)(x + i);
    float4 v1 = *(const float4*)(x + i + 4);
    ushort4 a = {f2bf(v0.x), f2bf(v0.y), f2bf(v0.z), f2bf(v0.w)};
    ushort4 b = {f2bf(v1.x), f2bf(v1.y), f2bf(v1.z), f2bf(v1.w)};
    *(ushort4*)(xb + i) = a;
    *(ushort4*)(xb + i + 4) = b;
}

__global__ __launch_bounds__(256) void k_wprep(const float* __restrict__ W,
                                               unsigned short* __restrict__ wtg) {
    int i = blockIdx.x * 256 + threadIdx.x;      // over NL*128*128
    if (i >= NL * DH * DH) return;
    int l = i >> 14, rem = i & 16383;
    int k = rem >> 7, c = rem & 127;
    wtg[(l << 14) + (c << 7) + k] = f2bf(W[i]);  // wtg[l][c][k] = W[l][k][c]
}

// ---- CSR build (bucketed) -------------------------------------------------

__global__ __launch_bounds__(256) void k_bcount(const int* __restrict__ dst,
                                                int* __restrict__ bcnt) {
    __shared__ int h[NBK];
    for (int i = threadIdx.x; i < NBK; i += 256) h[i] = 0;
    __syncthreads();
    int base = blockIdx.x * 4096;
#pragma unroll
    for (int k = 0; k < 16; ++k) {
        int i = base + k * 256 + threadIdx.x;
        if (i < ET) {
            int d = (i < NE) ? dst[i] : (i - NE);
            atomicAdd(&h[d >> 8], 1);
        }
    }
    __syncthreads();
    for (int i = threadIdx.x; i < NBK; i += 256)
        if (h[i]) atomicAdd(&bcnt[i], h[i]);
}

__global__ __launch_bounds__(512) void k_bscan(const int* __restrict__ bcnt,
                                               int* __restrict__ bbase,
                                               int* __restrict__ bcur,
                                               int* __restrict__ row_ptr) {
    __shared__ int sm[512];
    int t = threadIdx.x;
    int v = (t < NBK) ? bcnt[t] : 0;
    sm[t] = v;
    __syncthreads();
    for (int off = 1; off < 512; off <<= 1) {
        int u = (t >= off) ? sm[t - off] : 0;
        __syncthreads();
        sm[t] += u;
        __syncthreads();
    }
    if (t < NBK) { bbase[t] = sm[t] - v; bcur[t] = sm[t] - v; }
    if (t == 0) { bbase[NBK] = ET; row_ptr[NN] = ET; }
}

__global__ __launch_bounds__(512) void k_bscatter(const int* __restrict__ src,
                                                  const int* __restrict__ dst,
                                                  int* __restrict__ bcur,
                                                  int2* __restrict__ pairs) {
    __shared__ int lcnt[NBK];
    __shared__ int lbase[NBK];
    for (int i = threadIdx.x; i < NBK; i += 512) lcnt[i] = 0;
    __syncthreads();
    int base = blockIdx.x * 4096;
    int es[8], ed[8], er[8];
#pragma unroll
    for (int k = 0; k < 8; ++k) {
        int i = base + k * 512 + threadIdx.x;
        if (i < ET) {
            int s, d;
            if (i < NE) { s = src[i]; d = dst[i]; } else { s = d = i - NE; }
            es[k] = s; ed[k] = d;
            er[k] = atomicAdd(&lcnt[d >> 8], 1);
        } else {
            ed[k] = -1;
        }
    }
    __syncthreads();
    for (int i = threadIdx.x; i < NBK; i += 512)
        lbase[i] = lcnt[i] ? atomicAdd(&bcur[i], lcnt[i]) : 0;
    __syncthreads();
#pragma unroll
    for (int k = 0; k < 8; ++k) {
        if (ed[k] >= 0) {
            int bk = ed[k] >> 8;
            pairs[lbase[bk] + er[k]] = make_int2(es[k], ed[k]);
        }
    }
}

__global__ __launch_bounds__(256) void k_bfinal(const int2* __restrict__ pairs,
                                                const int* __restrict__ bbase,
                                                int* __restrict__ row_ptr,
                                                int* __restrict__ csr_src) {
    __shared__ int ldeg[256];
    __shared__ int lcur[256];
    __shared__ int sm[256];
    int b = blockIdx.x, t = threadIdx.x;
    int n0 = b << 8;
    int e0 = bbase[b], e1 = bbase[b + 1];
    ldeg[t] = 0;
    __syncthreads();
    for (int j = e0 + t; j < e1; j += 256)
        atomicAdd(&ldeg[pairs[j].y - n0], 1);
    __syncthreads();
    int v = ldeg[t];
    sm[t] = v;
    __syncthreads();
    for (int off = 1; off < 256; off <<= 1) {
        int u = (t >= off) ? sm[t - off] : 0;
        __syncthreads();
        sm[t] += u;
        __syncthreads();
    }
    int excl = sm[t] - v;
    lcur[t] = excl;
    int n = n0 + t;
    if (n < NN) row_ptr[n] = e0 + excl;
    __syncthreads();
    for (int j = e0 + t; j < e1; j += 256) {
        int2 p = pairs[j];
        int local = atomicAdd(&lcur[p.y - n0], 1);
        csr_src[e0 + local] = p.x;
    }
}

// ---- MFMA GEMM: xp = h @ W (bf16 in, fp32 acc) + fused dots ---------------
// Block: 4 waves x 16 rows = 64 rows, full 128 cols. B staged in LDS with
// XOR swizzle (byte ^= (col&7)<<4) for conflict-free ds_read_b128.

__global__ __launch_bounds__(256) void k_gemm(const unsigned short* __restrict__ A,
                                              const unsigned short* __restrict__ Wt,
                                              const float* __restrict__ a_s,
                                              const float* __restrict__ a_d,
                                              unsigned short* __restrict__ xpb,
                                              float* __restrict__ s_node,
                                              float* __restrict__ d_node) {
    __shared__ __align__(16) char lds[32768];
    int tid = threadIdx.x;
    int w = tid >> 6, l = tid & 63;
    int row0 = blockIdx.x * 64;
    {   // stage Wt[col][k] bf16 with swizzle; coalesced global reads
        int col = tid >> 1, seg = tid & 1;
        const char* srcp = (const char*)Wt + col * 256 + seg * 128;
#pragma unroll
        for (int i = 0; i < 8; ++i) {
            int off = seg * 128 + i * 16;
            *(uint4*)(lds + col * 256 + (off ^ ((col & 7) << 4))) =
                *(const uint4*)(srcp + i * 16);
        }
    }
    // A fragments: row = row0 + w*16 + (l&15), k = ks*32 + (l>>4)*8 + 0..7
    int arow = row0 + w * 16 + (l & 15);
    int arc = min(arow, NN - 1);
    const unsigned short* ap = A + (size_t)arc * DH + ((l >> 4) << 3);
    bf16x8 af[4];
#pragma unroll
    for (int ks = 0; ks < 4; ++ks)
        af[ks] = *(const bf16x8*)(ap + ks * 32);
    __syncthreads();

    f32x4 acc[8];
#pragma unroll
    for (int ct = 0; ct < 8; ++ct) acc[ct] = (f32x4){0.f, 0.f, 0.f, 0.f};
#pragma unroll
    for (int ct = 0; ct < 8; ++ct) {
        int col = ct * 16 + (l & 15);
        int cb = col * 256;
        int sw = (col & 7) << 4;
#pragma unroll
        for (int ks = 0; ks < 4; ++ks) {
            bf16x8 bfr = *(const bf16x8*)(lds + cb + ((ks * 64 + ((l >> 4) << 4)) ^ sw));
            acc[ct] = __builtin_amdgcn_mfma_f32_16x16x32_bf16(af[ks], bfr, acc[ct], 0, 0, 0);
        }
    }

    // fused dots: lane covers cols ct*16 + (l&15) for rows (l>>4)*4 + r
    float asv[8], adv[8];
#pragma unroll
    for (int ct = 0; ct < 8; ++ct) {
        asv[ct] = a_s[ct * 16 + (l & 15)];
        adv[ct] = a_d[ct * 16 + (l & 15)];
    }
    float ps[4] = {0.f, 0.f, 0.f, 0.f}, pd[4] = {0.f, 0.f, 0.f, 0.f};
#pragma unroll
    for (int ct = 0; ct < 8; ++ct)
#pragma unroll
        for (int r = 0; r < 4; ++r) {
            ps[r] = fmaf(acc[ct][r], asv[ct], ps[r]);
            pd[r] = fmaf(acc[ct][r], adv[ct], pd[r]);
        }
#pragma unroll
    for (int off = 8; off >= 1; off >>= 1)
#pragma unroll
        for (int r = 0; r < 4; ++r) {
            ps[r] += __shfl_xor(ps[r], off, 64);
            pd[r] += __shfl_xor(pd[r], off, 64);
        }
    int rbase = row0 + w * 16 + ((l >> 4) << 2);
    if ((l & 15) == 0) {
#pragma unroll
        for (int r = 0; r < 4; ++r) {
            int row = rbase + r;
            if (row < NN) { s_node[row] = ps[r]; d_node[row] = pd[r]; }
        }
    }
    // bf16 xp stores: 16-lane groups write 32B contiguous per (ct,r)
#pragma unroll
    for (int r = 0; r < 4; ++r) {
        int row = rbase + r;
        if (row < NN) {
            unsigned short* op = xpb + (size_t)row * DH + (l & 15);
#pragma unroll
            for (int ct = 0; ct < 8; ++ct)
                op[ct * 16] = f2bf(acc[ct][r]);
        }
    }
}

// ---- aggregation: wave per dst node, 2 edges/iteration --------------------

__global__ __launch_bounds__(256) void k_aggr(const unsigned short* __restrict__ xpb,
                                              const float* __restrict__ s_node,
                                              const float* __restrict__ d_node,
                                              const int* __restrict__ row_ptr,
                                              const int* __restrict__ csr_src,
                                              const float* __restrict__ bias,
                                              const float* __restrict__ gamma,
                                              const float* __restrict__ beta,
                                              const float* __restrict__ mean,
                                              const float* __restrict__ var,
                                              unsigned short* __restrict__ hout) {
    __shared__ float2 stash[4][128];
    int wid = threadIdx.x >> 6, lane = threadIdx.x & 63;
    int n = blockIdx.x * 4 + wid;
    if (n >= NN) return;
    int s0 = row_ptr[n], s1 = row_ptr[n + 1];
    int deg = s1 - s0;
    float dn = d_node[n];

    // lane-parallel: up to 128 edges -> registers (deg>128 handled in tail)
    int   sidx[2];
    float ev[2];
#pragma unroll
    for (int k = 0; k < 2; ++k) {
        int j = s0 + k * 64 + lane;
        int s = 0;
        float e = -1e30f;
        if (j < s1) {
            s = csr_src[j];
            float t = s_node[s] + dn;
            e = (t >= 0.f) ? t : 0.2f * t;
        }
        sidx[k] = s;
        ev[k] = e;
    }
    float mx = fmaxf(ev[0], ev[1]);
    for (int j = s0 + 128 + lane; j < s1; j += 64) {   // never in practice
        int s = csr_src[j];
        float t = s_node[s] + dn;
        t = (t >= 0.f) ? t : 0.2f * t;
        mx = fmaxf(mx, t);
    }
#pragma unroll
    for (int off = 32; off >= 1; off >>= 1)
        mx = fmaxf(mx, __shfl_xor(mx, off, 64));

    float w0 = (ev[0] > -1e29f) ? __expf(ev[0] - mx) : 0.f;
    float w1 = (ev[1] > -1e29f) ? __expf(ev[1] - mx) : 0.f;
    float denom = w0 + w1;
#pragma unroll
    for (int off = 32; off >= 1; off >>= 1)
        denom += __shfl_xor(denom, off, 64);

    stash[wid][lane]      = make_float2(w0, __int_as_float(sidx[0]));
    stash[wid][64 + lane] = make_float2(w1, __int_as_float(sidx[1]));

    // gather: half-wave per edge, ushort4 (8B) per lane, 2 edges/iteration
    float4 acc = make_float4(0.f, 0.f, 0.f, 0.f);
    int cnt = min(deg, 128);
    int cl = lane & 31, hi = lane >> 5;
    int cpair = (cnt + 1) & ~1;
#pragma unroll 4
    for (int jj = 0; jj < cpair; jj += 2) {
        float2 p = stash[wid][jj + hi];
        float w = p.x;
        int   s = __float_as_int(p.y);
        ushort4 v = ((const ushort4*)xpb)[((size_t)s << 5) + cl];
        acc.x = fmaf(w, bf2f(v.x), acc.x);
        acc.y = fmaf(w, bf2f(v.y), acc.y);
        acc.z = fmaf(w, bf2f(v.z), acc.z);
        acc.w = fmaf(w, bf2f(v.w), acc.w);
    }
    // tail fallback for deg>128 (statistically never; kept for correctness)
    for (int j = s0 + 128; j < s1; ++j) {
        int s = csr_src[j];
        float t = s_node[s] + dn;
        t = (t >= 0.f) ? t : 0.2f * t;
        float w = __expf(t - mx);
        denom += w;
        if (hi == 0) {
            ushort4 v = ((const ushort4*)xpb)[((size_t)s << 5) + cl];
            acc.x = fmaf(w, bf2f(v.x), acc.x);
            acc.y = fmaf(w, bf2f(v.y), acc.y);
            acc.z = fmaf(w, bf2f(v.z), acc.z);
            acc.w = fmaf(w, bf2f(v.w), acc.w);
        }
    }
    // combine the two half-waves (channels identical across halves)
    acc.x += __shfl_xor(acc.x, 32, 64);
    acc.y += __shfl_xor(acc.y, 32, 64);
    acc.z += __shfl_xor(acc.z, 32, 64);
    acc.w += __shfl_xor(acc.w, 32, 64);

    if (hi == 0) {
        float inv = 1.f / denom;     // denom >= 1 (self-loop term)
        int c = cl << 2;
        float4 bi = *(const float4*)(bias + c);
        float4 ga = *(const float4*)(gamma + c);
        float4 be = *(const float4*)(beta + c);
        float4 me = *(const float4*)(mean + c);
        float4 va = *(const float4*)(var + c);
        float o0 = fmaxf(acc.x * inv + bi.x, 0.f);
        float o1 = fmaxf(acc.y * inv + bi.y, 0.f);
        float o2 = fmaxf(acc.z * inv + bi.z, 0.f);
        float o3 = fmaxf(acc.w * inv + bi.w, 0.f);
        o0 = (o0 - me.x) * (ga.x * rsqrtf(va.x + 1e-5f)) + be.x;
        o1 = (o1 - me.y) * (ga.y * rsqrtf(va.y + 1e-5f)) + be.y;
        o2 = (o2 - me.z) * (ga.z * rsqrtf(va.z + 1e-5f)) + be.z;
        o3 = (o3 - me.w) * (ga.w * rsqrtf(va.w + 1e-5f)) + be.w;
        ushort4 ov = {f2bf(o0), f2bf(o1), f2bf(o2), f2bf(o3)};
        ((ushort4*)hout)[((size_t)n << 5) + cl] = ov;
    }
}

// ---- mean pool over sorted batch + final linear ---------------------------

__global__ __launch_bounds__(128) void k_pool1(const unsigned short* __restrict__ h,
                                               const int* __restrict__ batch,
                                               float* __restrict__ sums,
                                               int* __restrict__ cnts) {
    int c = threadIdx.x;
    int n0 = blockIdx.x * 64;
    int n1 = min(NN, n0 + 64);
    if (n0 >= NN) return;
    float acc = 0.f;
    int cur = batch[n0];
    int cnt = 0;
    for (int n = n0; n < n1; ++n) {
        int g = batch[n];
        if (g != cur) {
            atomicAdd(&sums[cur * DH + c], acc);
            if (c == 0) atomicAdd(&cnts[cur], cnt);
            acc = 0.f; cnt = 0; cur = g;
        }
        acc += bf2f(h[(size_t)n * DH + c]);
        ++cnt;
    }
    atomicAdd(&sums[cur * DH + c], acc);
    if (c == 0) atomicAdd(&cnts[cur], cnt);
}

__global__ __launch_bounds__(128) void k_pool2(const float* __restrict__ sums,
                                               const int* __restrict__ cnts,
                                               const float* __restrict__ lin_w,
                                               const float* __restrict__ lin_b,
                                               float* __restrict__ out) {
    __shared__ float sm[128];
    int g = blockIdx.x, c = threadIdx.x;
    float cnt = fmaxf((float)cnts[g], 1.f);
    sm[c] = (sums[g * DH + c] / cnt) * lin_w[c];
    __syncthreads();
    for (int off = 64; off >= 1; off >>= 1) {
        if (c < off) sm[c] += sm[c + off];
        __syncthreads();
    }
    if (c == 0) out[g] = sm[0] + lin_b[0];
}

// ---- launch ---------------------------------------------------------------

extern "C" void kernel_launch(void* const* d_in, const int* in_sizes, int n_in,
                              void* d_out, int out_size, void* d_ws, size_t ws_size,
                              hipStream_t stream) {
    const float* x     = (const float*)d_in[0];
    const int*   ei    = (const int*)d_in[1];
    const int*   batch = (const int*)d_in[2];
    const float* W     = (const float*)d_in[3];
    const float* a_src = (const float*)d_in[4];
    const float* a_dst = (const float*)d_in[5];
    const float* b     = (const float*)d_in[6];
    const float* bn_g  = (const float*)d_in[7];
    const float* bn_b  = (const float*)d_in[8];
    const float* bn_m  = (const float*)d_in[9];
    const float* bn_v  = (const float*)d_in[10];
    const float* lin_w = (const float*)d_in[11];
    const float* lin_b = (const float*)d_in[12];
    float* out = (float*)d_out;

    const int* srcp = ei;
    const int* dstp = ei + NE;

    char* wsp = (char*)d_ws;
    size_t off = 0;
    auto alloc = [&](size_t bytes) -> void* {
        void* p = wsp + off;
        off = (off + bytes + 511) & ~((size_t)511);
        return p;
    };
    unsigned short* xpb = (unsigned short*)alloc((size_t)NN * DH * 2);  // bf16 xp
    unsigned short* xb  = (unsigned short*)alloc((size_t)NN * DH * 2);  // bf16 x
    unsigned short* hb  = (unsigned short*)alloc((size_t)NN * DH * 2);  // bf16 h
    unsigned short* wtg = (unsigned short*)alloc((size_t)NL * DH * DH * 2);
    float* s_node  = (float*)alloc((size_t)NN * 4);
    float* d_node  = (float*)alloc((size_t)NN * 4);
    int*   row_ptr = (int*)alloc((size_t)(NN + 1) * 4);
    int*   csr_src = (int*)alloc((size_t)ET * 4);
    int2*  pairs   = (int2*)alloc((size_t)ET * 8);
    int*   bcnt    = (int*)alloc((size_t)NBK * 4);
    int*   bbase   = (int*)alloc((size_t)(NBK + 1) * 4);
    int*   bcur    = (int*)alloc((size_t)NBK * 4);
    float* sums    = (float*)alloc((size_t)NG * DH * 4);
    int*   cnts    = (int*)alloc((size_t)NG * 4);

    // prep: bf16 casts
    k_castx<<<(NN * DH) / 2048, 256, 0, stream>>>(x, xb);
    k_wprep<<<(NL * DH * DH + 255) / 256, 256, 0, stream>>>(W, wtg);

    // CSR build (bucketed; reused across the 5 layers)
    hipMemsetAsync(bcnt, 0, (size_t)NBK * 4, stream);
    k_bcount<<<(ET + 4095) / 4096, 256, 0, stream>>>(dstp, bcnt);
    k_bscan<<<1, 512, 0, stream>>>(bcnt, bbase, bcur, row_ptr);
    k_bscatter<<<(ET + 4095) / 4096, 512, 0, stream>>>(srcp, dstp, bcur, pairs);
    k_bfinal<<<NBK, 256, 0, stream>>>(pairs, bbase, row_ptr, csr_src);

    for (int l = 0; l < NL; ++l) {
        const unsigned short* hin = (l == 0) ? xb : hb;
        k_gemm<<<(NN + 63) / 64, 256, 0, stream>>>(hin, wtg + (size_t)l * DH * DH,
                                                   a_src + l * DH, a_dst + l * DH,
                                                   xpb, s_node, d_node);
        k_aggr<<<(NN + 3) / 4, 256, 0, stream>>>(xpb, s_node, d_node, row_ptr, csr_src,
                                                 b + l * DH, bn_g + l * DH, bn_b + l * DH,
                                                 bn_m + l * DH, bn_v + l * DH, hb);
    }

    hipMemsetAsync(sums, 0, (size_t)NG * DH * 4, stream);
    hipMemsetAsync(cnts, 0, (size_t)NG * 4, stream);
    k_pool1<<<(NN + 63) / 64, 128, 0, stream>>>(hb, batch, sums, cnts);
    k_pool2<<<NG, 128, 0, stream>>>(sums, cnts, lin_w, lin_b, out);
}